// Round 1
// baseline (445.438 us; speedup 1.0000x reference)
//
#include <hip/hip_runtime.h>

// out = LIF16(x @ W^T + b), x:[32768,512] f32, W:[512,512] f32, b:[512] f32.
//
// CORRECTNESS INVARIANT (rounds 0-8; do not break):
// Reference cur = SINGLE sequential ascending-k fp32 FMA chain (one
// accumulator per C element, k=0..511 ascending), then ONE bias add; LIF in
// fp32 RN, source identical to round-3/4/6/7 passing kernels (absmax 0.0).
// K-splits / reassociation forbidden.
//
// Round-9 theory: R8 shows VGPR_Count=88 with 128 live accs -> unified-file
// split, AGPR<->VGPR marshalling stealing VALU slots; plus 6 ds_read_b128/k
// and 3.1M LDS bank-conflict cycles. Restructure: per-lane tile 8 rows x
// 16 cols; B operands are wave-uniform -> scalar path (readfirstlane-uniform
// W pointer, s_load_dwordx2 into 2x16-v2f SGPR double buffer; v_fma_f32
// takes 1 SGPR operand). A-only LDS (k-major [BK][512], lane reads its 8
// contiguous rows = 2x ds_read_b128, 32B lane stride = conflict-free).
// VGPR demand ~190 -> no AGPR split. Grid (m=blockIdx.x 64, n=blockIdx.y 8):
// id%8 = m%8 -> the 8 co-resident n-blocks of each m-band share one XCD/L2.

typedef float v4f __attribute__((ext_vector_type(4)));
typedef float v2f __attribute__((ext_vector_type(2)));

#define KK 512
#define HH 512
#define BM 512          // rows per block (64 lanes x 8 rows, shared by 4 waves)
#define BN 64           // cols per block (4 waves x 16 cols)
#define BK 16           // k-chunk

__global__ __launch_bounds__(256, 2)
void lif_gemm_f32(const float* __restrict__ x,    // [B, K]
                  const float* __restrict__ W,    // [H, K]
                  const float* __restrict__ bias, // [H]
                  float* __restrict__ out)        // [B, H]
{
    __shared__ __align__(16) float As[2][BK][BM];   // 64 KiB, k-major

    const int tid  = threadIdx.x;
    const int lane = tid & 63;
    const int wv   = __builtin_amdgcn_readfirstlane(tid >> 6);  // wave id, uniform
    const int m0   = blockIdx.x * BM;                // m on x: id%8 == m%8 -> XCD share
    const int n0   = blockIdx.y * BN + wv * 16;      // wave's 16 cols, uniform

    // ---- staging map: thread t covers row (t>>1)+128p, k-bytes (t&1)*8..+7
    const int ra = tid >> 1;
    const int kc = (tid & 1) << 3;
    const float* xg = x + (size_t)(m0 + ra) * KK + kc;

    // ---- wave-uniform W pointer: 16 rows of W starting at col n0
    const float* wrow = W + (size_t)n0 * KK;

    float acc[8][16];
#pragma unroll
    for (int i = 0; i < 8; ++i)
#pragma unroll
        for (int c = 0; c < 16; ++c) acc[i][c] = 0.0f;

    // global prefetch of chunk 0 (8x dwordx4 per thread)
    v4f g[4][2];
#pragma unroll
    for (int p = 0; p < 4; ++p) {
        g[p][0] = *(const v4f*)(xg + p * 128 * KK);
        g[p][1] = *(const v4f*)(xg + p * 128 * KK + 4);
    }

    // scalar B double buffer: 16 cols x 2 k's per buffer (64 SGPRs total)
    v2f bb0[16], bb1[16];
#pragma unroll
    for (int c = 0; c < 16; ++c)
        bb0[c] = *(const v2f*)(wrow + c * KK);       // k = 0,1

    int pp = 0;
    for (int k0 = 0; k0 < KK; k0 += BK) {
        float (*Asp)[BM] = As[pp];

        // stage chunk k0 (regs -> LDS), k-major; odd/even lanes 2-way = free
#pragma unroll
        for (int p = 0; p < 4; ++p)
#pragma unroll
            for (int i = 0; i < 8; ++i)
                Asp[kc + i][ra + 128 * p] = (i < 4) ? g[p][0][i] : g[p][1][i - 4];
        __syncthreads();                 // single barrier per chunk (dbuf LDS)

        // prefetch next chunk's globals (tail: harmless reload)
        const int kn = (k0 + BK < KK) ? (k0 + BK) : k0;
#pragma unroll
        for (int p = 0; p < 4; ++p) {
            g[p][0] = *(const v4f*)(xg + p * 128 * KK + kn);
            g[p][1] = *(const v4f*)(xg + p * 128 * KK + kn + 4);
        }

        // A fragment double buffer: 2x ds_read_b128 per k
        v4f fa[2][2];
        fa[0][0] = *(const v4f*)&Asp[0][lane * 8];
        fa[0][1] = *(const v4f*)&Asp[0][lane * 8 + 4];

#pragma unroll
        for (int kp = 0; kp < 8; ++kp) {             // 2 k's per sub-chunk
            // issue next B pair (uniform scalar loads); clamp at very end
            const int knb0 = k0 + 2 * kp + 2;
            const int knb  = (knb0 <= KK - 2) ? knb0 : (KK - 2);
            if (kp & 1) {
#pragma unroll
                for (int c = 0; c < 16; ++c)
                    bb0[c] = *(const v2f*)(wrow + c * KK + knb);
            } else {
#pragma unroll
                for (int c = 0; c < 16; ++c)
                    bb1[c] = *(const v2f*)(wrow + c * KK + knb);
            }

#pragma unroll
            for (int h = 0; h < 2; ++h) {
                const int k  = 2 * kp + h;           // ascending k: load-bearing
                const int cb = k & 1;
                const int nb = cb ^ 1;
                if (k + 1 < BK) {
                    fa[nb][0] = *(const v4f*)&Asp[k + 1][lane * 8];
                    fa[nb][1] = *(const v4f*)&Asp[k + 1][lane * 8 + 4];
                }
                // 128 v_fma_f32: VGPR a, SGPR b, VGPR acc (1 SGPR/instr: legal)
#pragma unroll
                for (int i = 0; i < 8; ++i) {
                    const float a = (i < 4) ? fa[cb][0][i] : fa[cb][1][i - 4];
#pragma unroll
                    for (int c = 0; c < 16; ++c) {
                        const float b = (kp & 1) ? bb1[c][h] : bb0[c][h];
                        acc[i][c] = fmaf(a, b, acc[i][c]);
                    }
                }
            }
        }
        pp ^= 1;
    }

    // Epilogue: + bias (single fp32 add), 16-step fp32 LIF (identical source
    // to the round-3/4/6/7 passing kernels), store count/16.
    float bs[16];
#pragma unroll
    for (int c = 0; c < 16; ++c)
        bs[c] = bias[n0 + c];                        // uniform -> s_load

    const int rbase = m0 + lane * 8;
#pragma unroll
    for (int i = 0; i < 8; ++i) {
        float res[16];
#pragma unroll
        for (int c = 0; c < 16; ++c) {
            const float cur = acc[i][c] + bs[c];
            float v = 0.0f;
            int cnt = 0;
#pragma unroll
            for (int t = 0; t < 16; ++t) {
                v = v + (cur - v) * 0.5f;    // == v + (cur - v)/2, RN-identical
                const bool s = (v >= 1.0f);  // == (v - 1.0f) >= 0 in fp32
                cnt += s ? 1 : 0;
                v = s ? 0.0f : v;
            }
            res[c] = (float)cnt * 0.0625f;   // exact multiple of 1/16
        }
        float* op = out + (size_t)(rbase + i) * HH + n0;
#pragma unroll
        for (int q = 0; q < 4; ++q)
            *(v4f*)(op + q * 4) = (v4f){res[4*q], res[4*q+1], res[4*q+2], res[4*q+3]};
    }
}

extern "C" void kernel_launch(void* const* d_in, const int* in_sizes, int n_in,
                              void* d_out, int out_size, void* d_ws, size_t ws_size,
                              hipStream_t stream) {
    const float* x    = (const float*)d_in[0];
    const float* W    = (const float*)d_in[1];
    const float* bias = (const float*)d_in[2];
    float* out = (float*)d_out;

    const int B = in_sizes[0] / KK;      // 32768

    dim3 grid(B / BM, HH / BN);          // (64, 8) = 512 blocks = 2/CU exactly
    dim3 block(256);
    lif_gemm_f32<<<grid, block, 0, stream>>>(x, W, bias, out);
}

// Round 2
// 326.013 us; speedup vs baseline: 1.3663x; 1.3663x over previous
//
#include <hip/hip_runtime.h>

// out = LIF16(x @ W^T + b), x:[32768,512] f32, W:[512,512] f32, b:[512] f32.
//
// CORRECTNESS INVARIANT (rounds 0-9; do not break):
// Reference cur = SINGLE sequential ascending-k fp32 FMA chain (one
// accumulator per C element, k=0..511 ascending), then ONE bias add; LIF in
// fp32 RN, source identical to round-3/4/6/7 passing kernels (absmax 0.0).
// K-splits / reassociation forbidden.
//
// Round-10: R9's three failures, fixed explicitly:
//  1. B scalar path via inline-asm s_load_dwordx2 (compiler never promotes
//     non-invariant uniform loads to s_load). Dbuf per 2-k group; explicit
//     s_waitcnt lgkmcnt(0) + sched_barrier(0) per group (rule #18). Sound
//     with compiler's counted ds waits since DS completes in-order among DS.
//  2. Lane L owns rows {4L..4L+3, 256+4L..4L+3}: the two ds_read_b128/k are
//     lane-consecutive 16B (1KB contiguous per wave) -> conflict-free.
//     (R9's lane*8 stride hit 4 banks = 16-way conflict, 12.6M cycles.)
//  3. Epilogue LDS transpose (reuse As, 2 halves of 256x64, XOR-swizzled
//     chunks) -> stores are 16-lane x 16B contiguous; WRITE_SIZE back to
//     64MB (R9's scattered per-lane-row stores doubled write traffic).

typedef float v4f __attribute__((ext_vector_type(4)));
typedef float v2f __attribute__((ext_vector_type(2)));

#define KK 512
#define HH 512
#define BM 512          // rows per block (lane L: 4L..4L+3, 256+4L..+3)
#define BN 64           // cols per block (4 waves x 16 cols)
#define BK 16           // k-chunk

// scalar load of 2 consecutive floats: dst <- *(base + off_bytes)
#define SL2(dst, base, off) \
    asm volatile("s_load_dwordx2 %0, %1, %2" : "=&s"(dst) : "s"(base), "i"(off))

__global__ __launch_bounds__(256, 2)
void lif_gemm_f32(const float* __restrict__ x,    // [B, K]
                  const float* __restrict__ W,    // [H, K]
                  const float* __restrict__ bias, // [H]
                  float* __restrict__ out)        // [B, H]
{
    __shared__ __align__(16) float As[2][BK][BM];   // 64 KiB, k-major

    const int tid  = threadIdx.x;
    const int lane = tid & 63;
    const int wv   = __builtin_amdgcn_readfirstlane(tid >> 6);  // uniform
    const int m0   = blockIdx.x * BM;   // m on x: id%8 == m%8 -> n-blocks share XCD
    const int nb0  = blockIdx.y * BN;
    const int n0   = nb0 + wv * 16;     // wave's 16 cols, uniform

    // staging map: thread t covers row (t>>1)+128p, k (t&1)*8 .. +7
    const int ra = tid >> 1;
    const int kc = (tid & 1) << 3;
    const float* xg = x + (size_t)(m0 + ra) * KK + kc;

    // wave-uniform W base: 16 rows of W starting at output col n0
    const float* wrow = W + (size_t)n0 * KK;

    float acc[8][16];
#pragma unroll
    for (int i = 0; i < 8; ++i)
#pragma unroll
        for (int c = 0; c < 16; ++c) acc[i][c] = 0.0f;

    // B scalar double buffer (64 SGPRs): prologue loads k=0,1 into bb0
    v2f bb0[16], bb1[16];
#pragma unroll
    for (int c = 0; c < 16; ++c) SL2(bb0[c], wrow, c * 2048);

    // global prefetch of chunk 0 (8x dwordx4 per thread)
    v4f g[4][2];
#pragma unroll
    for (int p = 0; p < 4; ++p) {
        g[p][0] = *(const v4f*)(xg + (size_t)p * 128 * KK);
        g[p][1] = *(const v4f*)(xg + (size_t)p * 128 * KK + 4);
    }

    int pp = 0;
    for (int k0 = 0; k0 < KK; k0 += BK) {
        float (*Asp)[BM] = As[pp];

        // stage chunk k0 (regs -> LDS), k-major; lane pairs 2-way = free
#pragma unroll
        for (int p = 0; p < 4; ++p)
#pragma unroll
            for (int i = 0; i < 8; ++i)
                Asp[kc + i][ra + 128 * p] = (i < 4) ? g[p][0][i] : g[p][1][i - 4];
        __syncthreads();                 // single barrier per chunk (dbuf LDS)

        // prefetch next chunk's globals (tail: harmless reload)
        const int kn = (k0 + BK < KK) ? (k0 + BK) : k0;
#pragma unroll
        for (int p = 0; p < 4; ++p) {
            g[p][0] = *(const v4f*)(xg + (size_t)p * 128 * KK + kn);
            g[p][1] = *(const v4f*)(xg + (size_t)p * 128 * KK + kn + 4);
        }

        // A fragment dbuf: 2x ds_read_b128/k, lane-consecutive -> no conflict
        v4f fa[2][2];
        fa[0][0] = *(const v4f*)&Asp[0][lane * 4];
        fa[0][1] = *(const v4f*)&Asp[0][256 + lane * 4];

#pragma unroll
        for (int kp = 0; kp < 8; ++kp) {             // 2 k's per group
            // bb[kp&1] (issued last group) + fa (issued last group) ready:
            asm volatile("s_waitcnt lgkmcnt(0)");
            __builtin_amdgcn_sched_barrier(0);       // rule #18: pin FMAs after

            // issue next B pair into the other buffer (clamped at the end)
            const int knb0 = k0 + 2 * kp + 2;
            const int knb  = (knb0 <= KK - 2) ? knb0 : (KK - 2);
            const float* pb = wrow + knb;
            if (kp & 1) {
#pragma unroll
                for (int c = 0; c < 16; ++c) SL2(bb0[c], pb, c * 2048);
            } else {
#pragma unroll
                for (int c = 0; c < 16; ++c) SL2(bb1[c], pb, c * 2048);
            }

#pragma unroll
            for (int h = 0; h < 2; ++h) {
                const int k  = 2 * kp + h;           // ascending k: load-bearing
                const int cb = k & 1;
                const int nb = cb ^ 1;
                if (k + 1 < BK) {
                    fa[nb][0] = *(const v4f*)&Asp[k + 1][lane * 4];
                    fa[nb][1] = *(const v4f*)&Asp[k + 1][256 + lane * 4];
                }
                // 128 v_fma_f32: VGPR a, SGPR b (1 SGPR/instr: legal), VGPR acc
#pragma unroll
                for (int i = 0; i < 8; ++i) {
                    const float a = (i < 4) ? fa[cb][0][i] : fa[cb][1][i - 4];
#pragma unroll
                    for (int c = 0; c < 16; ++c) {
                        const float b = (kp & 1) ? bb1[c][h] : bb0[c][h];
                        acc[i][c] = fmaf(a, b, acc[i][c]);
                    }
                }
            }
        }
        pp ^= 1;
    }

    // Epilogue: + bias (single fp32 add), 16-step fp32 LIF (identical source
    // to the round-3/4/6/7 passing kernels), LDS transpose, coalesced store.
    float bs[16];
#pragma unroll
    for (int c = 0; c < 16; ++c)
        bs[c] = bias[n0 + c];

    float* Ls = (float*)As;              // reuse 64 KiB: 256 rows x 64 cols
    const int rr = tid >> 4;             // 0..15
    const int cq = tid & 15;             // 0..15

#pragma unroll
    for (int h2 = 0; h2 < 2; ++h2) {     // halves: rows 0..255, 256..511
        float res[4][16];
#pragma unroll
        for (int i2 = 0; i2 < 4; ++i2) {
#pragma unroll
            for (int c = 0; c < 16; ++c) {
                const float cur = acc[h2 * 4 + i2][c] + bs[c];
                float v = 0.0f;
                int cnt = 0;
#pragma unroll
                for (int t = 0; t < 16; ++t) {
                    v = v + (cur - v) * 0.5f;    // == v + (cur - v)/2, RN-identical
                    const bool s = (v >= 1.0f);  // == (v - 1.0f) >= 0 in fp32
                    cnt += s ? 1 : 0;
                    v = s ? 0.0f : v;
                }
                res[i2][c] = (float)cnt * 0.0625f;   // exact multiple of 1/16
            }
        }
        __syncthreads();   // prior As/Ls reads complete before overwrite

        // write: lane L -> rows 4L+i2, col-chunks wv*4+q, XOR-swizzled
#pragma unroll
        for (int i2 = 0; i2 < 4; ++i2) {
            const int r = 4 * lane + i2;
#pragma unroll
            for (int q = 0; q < 4; ++q) {
                const int ch = (r * 16 + wv * 4 + q) ^ (lane & 7);
                *(v4f*)(Ls + ch * 4) =
                    (v4f){res[i2][4*q], res[i2][4*q+1], res[i2][4*q+2], res[i2][4*q+3]};
            }
        }
        __syncthreads();

        // read + store: 16-lane groups write 256B contiguous per row
#pragma unroll
        for (int it = 0; it < 16; ++it) {
            const int r  = it * 16 + rr;
            const int ch = (r * 16 + cq) ^ ((r >> 2) & 7);
            const v4f val = *(const v4f*)(Ls + ch * 4);
            float* op = out + (size_t)(m0 + h2 * 256 + r) * HH + nb0 + cq * 4;
            *(v4f*)op = val;
        }
    }
}

extern "C" void kernel_launch(void* const* d_in, const int* in_sizes, int n_in,
                              void* d_out, int out_size, void* d_ws, size_t ws_size,
                              hipStream_t stream) {
    const float* x    = (const float*)d_in[0];
    const float* W    = (const float*)d_in[1];
    const float* bias = (const float*)d_in[2];
    float* out = (float*)d_out;

    const int B = in_sizes[0] / KK;      // 32768

    dim3 grid(B / BM, HH / BN);          // (64, 8) = 512 blocks = 2/CU exactly
    dim3 block(256);
    lif_gemm_f32<<<grid, block, 0, stream>>>(x, W, bias, out);
}

// Round 5
// 324.878 us; speedup vs baseline: 1.3711x; 1.0035x over previous
//
#include <hip/hip_runtime.h>

// out = LIF16(x @ W^T + b), x:[32768,512] f32, W:[512,512] f32, b:[512] f32.
//
// CORRECTNESS INVARIANT (rounds 0-12; do not break):
// Reference cur = SINGLE sequential ascending-k fp32 FMA chain (one
// accumulator per C element, k=0..511 ascending), then ONE bias add; LIF in
// fp32 RN, source identical to round-3/4/6/7 passing kernels (absmax 0.0).
// K-splits / reassociation forbidden.
//
// Round-13: R11/R12 (scalar-B + launch_bounds(256,4)) SIGABRT'd twice with
// no locatable fault; abandoned per two-strike rule. Back to the PASSING
// round-0 structure (no inline asm, compiler-scheduled waits, absmax 0.0),
// applying ONLY the occupancy lever that R10's counters justified: both R0
// and R10 idle 33-40% at 2 waves/SIMD (grid 512 = 2 blocks/CU caps it).
// Change: BM 256->128 (per-thread 8x8, acc 64), LDS 50->33KB, grid 1024 =
// 4 blocks/CU, __launch_bounds__(256,4) -> 4 waves/SIMD. Every compiler
// lgkmcnt/barrier stall now has 3 sibling waves to hide behind.

typedef float v4f __attribute__((ext_vector_type(4)));

#define BM 128
#define BN 128
#define BK 16
#define LDA (BM + 4)   // 132
#define LDB (BN + 4)   // 132

__global__ __launch_bounds__(256, 4)
void lif_gemm_f32(const float* __restrict__ x,    // [B, K]
                  const float* __restrict__ W,    // [H, K]
                  const float* __restrict__ bias, // [H]
                  float* __restrict__ out,        // [B, H]
                  int K, int H)
{
    __shared__ __align__(16) float As[2][BK][LDA];   // 16.5 KiB
    __shared__ __align__(16) float Bs[2][BK][LDB];   // 16.5 KiB

    const int tid = threadIdx.x;
    const int tm  = tid & 15;        // rows tm*4 + {0,64}
    const int tn  = tid >> 4;        // cols tn*4 and 64+tn*4
    const int n0  = blockIdx.x * BN;
    const int m0  = blockIdx.y * BM;

    const int ra = tid >> 1;         // 0..127
    const int kc = (tid & 1) << 3;   // 0 or 8

    const float* xg = x + (size_t)(m0 + ra) * K + kc;
    const float* wg = W + (size_t)(n0 + ra) * K + kc;

    float acc[8][8];                 // plain scalars: no pair constraints
#pragma unroll
    for (int i = 0; i < 8; ++i)
#pragma unroll
        for (int j = 0; j < 8; ++j)
            acc[i][j] = 0.0f;

    // prefetch tile 0 into registers
    v4f a0 = *(const v4f*)(xg);
    v4f a1 = *(const v4f*)(xg + 4);
    v4f b0 = *(const v4f*)(wg);
    v4f b1 = *(const v4f*)(wg + 4);

    int pp = 0;
    for (int k0 = 0; k0 < K; k0 += BK) {
        float (*Asp)[LDA] = As[pp];
        float (*Bsp)[LDB] = Bs[pp];

        // stage tile k0 (held in regs) -> LDS buf pp
#pragma unroll
        for (int i = 0; i < 4; ++i) {
            Asp[kc + i][ra]     = a0[i];
            Asp[kc + 4 + i][ra] = a1[i];
            Bsp[kc + i][ra]     = b0[i];
            Bsp[kc + 4 + i][ra] = b1[i];
        }
        __syncthreads();             // single barrier per iteration

        // prefetch tile k0+BK (whole compute section to land)
        const int kn = (k0 + BK < K) ? (k0 + BK) : k0;  // tail: harmless reload
        a0 = *(const v4f*)(xg + kn);
        a1 = *(const v4f*)(xg + kn + 4);
        b0 = *(const v4f*)(wg + kn);
        b1 = *(const v4f*)(wg + kn + 4);

        // fragment regs, double-buffered across k (reads issue one k early)
        v4f fa0[2], fa1[2], fb0[2], fb1[2];
        fa0[0] = *(const v4f*)&Asp[0][tm * 4];
        fa1[0] = *(const v4f*)&Asp[0][64 + tm * 4];
        fb0[0] = *(const v4f*)&Bsp[0][tn * 4];
        fb1[0] = *(const v4f*)&Bsp[0][64 + tn * 4];

#pragma unroll
        for (int k = 0; k < BK; ++k) {   // ascending k: order is load-bearing
            const int cb = k & 1, nb = cb ^ 1;
            if (k + 1 < BK) {
                fa0[nb] = *(const v4f*)&Asp[k + 1][tm * 4];
                fa1[nb] = *(const v4f*)&Asp[k + 1][64 + tm * 4];
                fb0[nb] = *(const v4f*)&Bsp[k + 1][tn * 4];
                fb1[nb] = *(const v4f*)&Bsp[k + 1][64 + tn * 4];
            }
            // 64 scalar v_fma_f32, operands indexed directly from frag regs
#pragma unroll
            for (int i = 0; i < 8; ++i) {
                const float a = (i < 4) ? fa0[cb][i] : fa1[cb][i - 4];
#pragma unroll
                for (int j = 0; j < 8; ++j) {
                    const float b = (j < 4) ? fb0[cb][j] : fb1[cb][j - 4];
                    acc[i][j] = fmaf(a, b, acc[i][j]);
                }
            }
        }
        pp ^= 1;
    }

    // Epilogue: + bias (single fp32 add), 16-step fp32 LIF (identical source
    // to the round-3/4/6/7 passing kernels), store count/16.
    float bcol[8];
#pragma unroll
    for (int j = 0; j < 8; ++j) {
        const int col = (j < 4) ? (tn * 4 + j) : (64 + tn * 4 + (j - 4));
        bcol[j] = bias[n0 + col];
    }

#pragma unroll
    for (int i = 0; i < 8; ++i) {
        const int row = m0 + 64 * (i >> 2) + tm * 4 + (i & 3);
        float res[8];
#pragma unroll
        for (int j = 0; j < 8; ++j) {
            const float cur = acc[i][j] + bcol[j];
            float v = 0.0f;
            int cnt = 0;
#pragma unroll
            for (int t = 0; t < 16; ++t) {
                v = v + (cur - v) * 0.5f;    // == v + (cur - v)/2, RN-identical
                const bool s = (v >= 1.0f);  // == (v - 1.0f) >= 0 in fp32
                cnt += s ? 1 : 0;
                v = s ? 0.0f : v;
            }
            res[j] = (float)cnt * 0.0625f;   // exact multiple of 1/16
        }
        float* op = out + (size_t)row * H + n0;
        *(v4f*)(op + tn * 4)      = (v4f){res[0], res[1], res[2], res[3]};
        *(v4f*)(op + 64 + tn * 4) = (v4f){res[4], res[5], res[6], res[7]};
    }
}

extern "C" void kernel_launch(void* const* d_in, const int* in_sizes, int n_in,
                              void* d_out, int out_size, void* d_ws, size_t ws_size,
                              hipStream_t stream) {
    const float* x    = (const float*)d_in[0];
    const float* W    = (const float*)d_in[1];
    const float* bias = (const float*)d_in[2];
    float* out = (float*)d_out;

    const int K = 512;
    const int H = 512;
    const int B = in_sizes[0] / K;   // 32768

    dim3 grid(H / BN, B / BM);       // (4, 256) = 1024 blocks = 4/CU exactly
    dim3 block(256);
    lif_gemm_f32<<<grid, block, 0, stream>>>(x, W, bias, out, K, H);
}

// Round 6
// 318.470 us; speedup vs baseline: 1.3987x; 1.0201x over previous
//
#include <hip/hip_runtime.h>

// out = LIF16(x @ W^T + b), x:[32768,512] f32, W:[512,512] f32, b:[512] f32.
//
// CORRECTNESS INVARIANT (rounds 0-13; do not break):
// Reference cur = SINGLE sequential ascending-k fp32 FMA chain (one
// accumulator per C element, k=0..511 ascending), then ONE bias add; LIF in
// fp32 RN, source identical to round-3/4/6/7 passing kernels (absmax 0.0).
// K-splits / reassociation forbidden. v_pk_fma_f32 is legal: each packed
// lane is an independent per-output ascending-k chain, bit-identical.
//
// Round-14: three structurally different kernels (R0/R10/R13) all pin VALU
// busy at ~165us vs the 109us scalar v_fma issue floor; memory path and
// occupancy levers both exhausted (R10 FETCH=compulsory, R13 occ 19->31%
// with flat time). Remaining lever: halve FMA issue with v_pk_fma_f32.
// R7's pk attempt died of marshalling (fat tile, AGPR split, {a,a}+{b,b}
// broadcasts); here acc pairs along N so B operands are natural 64-bit
// subregisters of the ds_read_b128 fragments (fb0.xy/fb0.zw, no movs) and
// only A needs {a,a} (8/k, op_sel-foldable, worst case 8 movs). Everything
// else byte-identical to passing R13.

typedef float v4f __attribute__((ext_vector_type(4)));
typedef float v2f __attribute__((ext_vector_type(2)));

#define BM 128
#define BN 128
#define BK 16
#define LDA (BM + 4)   // 132
#define LDB (BN + 4)   // 132

__global__ __launch_bounds__(256, 4)
void lif_gemm_f32(const float* __restrict__ x,    // [B, K]
                  const float* __restrict__ W,    // [H, K]
                  const float* __restrict__ bias, // [H]
                  float* __restrict__ out,        // [B, H]
                  int K, int H)
{
    __shared__ __align__(16) float As[2][BK][LDA];   // 16.5 KiB
    __shared__ __align__(16) float Bs[2][BK][LDB];   // 16.5 KiB

    const int tid = threadIdx.x;
    const int tm  = tid & 15;        // rows tm*4 + {0,64}
    const int tn  = tid >> 4;        // cols tn*4 and 64+tn*4
    const int n0  = blockIdx.x * BN;
    const int m0  = blockIdx.y * BM;

    const int ra = tid >> 1;         // 0..127
    const int kc = (tid & 1) << 3;   // 0 or 8

    const float* xg = x + (size_t)(m0 + ra) * K + kc;
    const float* wg = W + (size_t)(n0 + ra) * K + kc;

    // acc paired along N: acc2[i][p] = cols {2p, 2p+1} of the 8-col group
    v2f acc2[8][4];
#pragma unroll
    for (int i = 0; i < 8; ++i)
#pragma unroll
        for (int p = 0; p < 4; ++p)
            acc2[i][p] = (v2f){0.0f, 0.0f};

    // prefetch tile 0 into registers
    v4f a0 = *(const v4f*)(xg);
    v4f a1 = *(const v4f*)(xg + 4);
    v4f b0 = *(const v4f*)(wg);
    v4f b1 = *(const v4f*)(wg + 4);

    int pp = 0;
    for (int k0 = 0; k0 < K; k0 += BK) {
        float (*Asp)[LDA] = As[pp];
        float (*Bsp)[LDB] = Bs[pp];

        // stage tile k0 (held in regs) -> LDS buf pp
#pragma unroll
        for (int i = 0; i < 4; ++i) {
            Asp[kc + i][ra]     = a0[i];
            Asp[kc + 4 + i][ra] = a1[i];
            Bsp[kc + i][ra]     = b0[i];
            Bsp[kc + 4 + i][ra] = b1[i];
        }
        __syncthreads();             // single barrier per iteration

        // prefetch tile k0+BK (whole compute section to land)
        const int kn = (k0 + BK < K) ? (k0 + BK) : k0;  // tail: harmless reload
        a0 = *(const v4f*)(xg + kn);
        a1 = *(const v4f*)(xg + kn + 4);
        b0 = *(const v4f*)(wg + kn);
        b1 = *(const v4f*)(wg + kn + 4);

        // fragment regs, double-buffered across k (reads issue one k early)
        v4f fa0[2], fa1[2], fb0[2], fb1[2];
        fa0[0] = *(const v4f*)&Asp[0][tm * 4];
        fa1[0] = *(const v4f*)&Asp[0][64 + tm * 4];
        fb0[0] = *(const v4f*)&Bsp[0][tn * 4];
        fb1[0] = *(const v4f*)&Bsp[0][64 + tn * 4];

#pragma unroll
        for (int k = 0; k < BK; ++k) {   // ascending k: order is load-bearing
            const int cb = k & 1, nb = cb ^ 1;
            if (k + 1 < BK) {
                fa0[nb] = *(const v4f*)&Asp[k + 1][tm * 4];
                fa1[nb] = *(const v4f*)&Asp[k + 1][64 + tm * 4];
                fb0[nb] = *(const v4f*)&Bsp[k + 1][tn * 4];
                fb1[nb] = *(const v4f*)&Bsp[k + 1][64 + tn * 4];
            }
            // B pairs: natural 64-bit subregisters of the b128 fragments
            const v2f bp[4] = {
                __builtin_shufflevector(fb0[cb], fb0[cb], 0, 1),
                __builtin_shufflevector(fb0[cb], fb0[cb], 2, 3),
                __builtin_shufflevector(fb1[cb], fb1[cb], 0, 1),
                __builtin_shufflevector(fb1[cb], fb1[cb], 2, 3),
            };
            // 32 v_pk_fma_f32 (64 lane-FMAs); each packed lane keeps its own
            // sequential ascending-k chain -> bit-identical to scalar fmaf
#pragma unroll
            for (int i = 0; i < 8; ++i) {
                const float a = (i < 4) ? fa0[cb][i] : fa1[cb][i - 4];
                const v2f aa = {a, a};   // op_sel-foldable broadcast
#pragma unroll
                for (int p = 0; p < 4; ++p)
                    acc2[i][p] = __builtin_elementwise_fma(aa, bp[p], acc2[i][p]);
            }
        }
        pp ^= 1;
    }

    // Epilogue: + bias (single fp32 add), 16-step fp32 LIF (identical source
    // to the round-3/4/6/7 passing kernels), store count/16.
    float bcol[8];
#pragma unroll
    for (int j = 0; j < 8; ++j) {
        const int col = (j < 4) ? (tn * 4 + j) : (64 + tn * 4 + (j - 4));
        bcol[j] = bias[n0 + col];
    }

#pragma unroll
    for (int i = 0; i < 8; ++i) {
        const int row = m0 + 64 * (i >> 2) + tm * 4 + (i & 3);
        float res[8];
#pragma unroll
        for (int j = 0; j < 8; ++j) {
            const float cur = acc2[i][j >> 1][j & 1] + bcol[j];
            float v = 0.0f;
            int cnt = 0;
#pragma unroll
            for (int t = 0; t < 16; ++t) {
                v = v + (cur - v) * 0.5f;    // == v + (cur - v)/2, RN-identical
                const bool s = (v >= 1.0f);  // == (v - 1.0f) >= 0 in fp32
                cnt += s ? 1 : 0;
                v = s ? 0.0f : v;
            }
            res[j] = (float)cnt * 0.0625f;   // exact multiple of 1/16
        }
        float* op = out + (size_t)row * H + n0;
        *(v4f*)(op + tn * 4)      = (v4f){res[0], res[1], res[2], res[3]};
        *(v4f*)(op + 64 + tn * 4) = (v4f){res[4], res[5], res[6], res[7]};
    }
}

extern "C" void kernel_launch(void* const* d_in, const int* in_sizes, int n_in,
                              void* d_out, int out_size, void* d_ws, size_t ws_size,
                              hipStream_t stream) {
    const float* x    = (const float*)d_in[0];
    const float* W    = (const float*)d_in[1];
    const float* bias = (const float*)d_in[2];
    float* out = (float*)d_out;

    const int K = 512;
    const int H = 512;
    const int B = in_sizes[0] / K;   // 32768

    dim3 grid(H / BN, B / BM);       // (4, 256) = 1024 blocks = 4/CU exactly
    dim3 block(256);
    lif_gemm_f32<<<grid, block, 0, stream>>>(x, W, bias, out, K, H);
}